// Round 1
// baseline (1229.706 us; speedup 1.0000x reference)
//
#include <hip/hip_runtime.h>

// ---------------------------------------------------------------------------
// Complex 4D CNN (LASLNNet):
//   L1: cconv4d 1->32,  k=3, s=2, p=0 : (4,1,20^4)  -> (4,32,9^4)   + CReLU
//   L2: cconv4d 32->64, k=3, s=1, p=1 : (4,32,9^4)  -> (4,64,9^4)   + CReLU
//   L3: cconv4d 64->128,k=1           : (4,64,9^4)  -> (4,128,9^4)  + CReLU
//   L4: cconv4d 128->128,k=1          :              -> (4,128,9^4) + CReLU
//   L5: cconv4d 128->64, k=1, s=2     : (4,128,9^4) -> (4,64,5^4)   + CReLU
//   FC: (4,64,625) @ fcw(625) (+fcb for real part) -> out (2,4,64)
// All fp32. Weights pre-transposed into [cg][tap][ci][u][{r,i}] so LDS stage
// is contiguous and inner reads are wave-uniform float4 broadcasts.
// ---------------------------------------------------------------------------

__global__ __launch_bounds__(256) void transpose_w_kernel(
    const float* __restrict__ wr, const float* __restrict__ wi,
    float* __restrict__ dst, int Cout, int Cin, int T, int G) {
  int n = Cout * Cin * T;
  for (int idx = blockIdx.x * blockDim.x + threadIdx.x; idx < n;
       idx += gridDim.x * blockDim.x) {
    int t = idx % T;
    int ci = (idx / T) % Cin;
    int co = idx / (T * Cin);
    int cg = co / G, u = co % G;
    int d = ((((cg * T + t) * Cin) + ci) * G + u) * 2;
    dst[d] = wr[idx];
    dst[d + 1] = wi[idx];
  }
}

// ---- Layer 1: Cin=1, Cout=32 (16 per block), k=3, s=2, in 20^4, out 9^4 ----
__global__ __launch_bounds__(256) void cconv_l1(
    const float* __restrict__ xr, const float* __restrict__ xi,
    const float* __restrict__ wt, const float* __restrict__ br,
    const float* __restrict__ bi, float* __restrict__ yr,
    float* __restrict__ yi) {
  __shared__ __align__(16) float lw[81 * 16 * 2];  // [t][u][ri]
  const int tid = threadIdx.x;
  const int cg = blockIdx.y;  // 0..1 -> co = cg*16+u
  const int b = blockIdx.z;
  for (int i = tid; i < 2592; i += 256) lw[i] = wt[cg * 2592 + i];
  __syncthreads();

  int pos = blockIdx.x * 256 + tid;
  bool valid = pos < 6561;
  int p = valid ? pos : 6560;
  int d1 = p / 729, r = p % 729;
  int d2 = r / 81;
  r %= 81;
  int d3 = r / 9, d4 = r % 9;
  const int base = b * 160000 + d1 * 16000 + d2 * 800 + d3 * 40 + d4 * 2;
  const float* xrb = xr + base;
  const float* xib = xi + base;

  float2 acc[16];
#pragma unroll
  for (int u = 0; u < 16; ++u) acc[u] = make_float2(0.f, 0.f);

  for (int j1 = 0; j1 < 3; ++j1)
    for (int j2 = 0; j2 < 3; ++j2)
      for (int j3 = 0; j3 < 3; ++j3)
#pragma unroll
        for (int j4 = 0; j4 < 3; ++j4) {
          int t = ((j1 * 3 + j2) * 3 + j3) * 3 + j4;
          int xo = j1 * 8000 + j2 * 400 + j3 * 20 + j4;
          float xrv = xrb[xo], xiv = xib[xo];
          const float2* wv = (const float2*)&lw[t * 32];
#pragma unroll
          for (int u = 0; u < 16; ++u) {
            float2 w = wv[u];
            acc[u].x += xrv * w.x - xiv * w.y;
            acc[u].y += xrv * w.y + xiv * w.x;
          }
        }

  if (valid) {
#pragma unroll
    for (int u = 0; u < 16; ++u) {
      int co = cg * 16 + u;
      float vr = fmaxf(acc[u].x + br[co], 0.f);
      float vi = fmaxf(acc[u].y + bi[co], 0.f);
      yr[(b * 32 + co) * 6561 + p] = vr;
      yi[(b * 32 + co) * 6561 + p] = vi;
    }
  }
}

// ---- Layer 2: Cin=32, Cout=64 (8 per block), k=3, s=1, pad=1, 9^4 ----------
__global__ __launch_bounds__(256) void cconv_k3(
    const float* __restrict__ xr, const float* __restrict__ xi,
    const float* __restrict__ wt, const float* __restrict__ br,
    const float* __restrict__ bi, float* __restrict__ yr,
    float* __restrict__ yi) {
  __shared__ __align__(16) float lw[512];  // one tap slice: [ci=32][u=8][ri=2]
  const int tid = threadIdx.x;
  const int cg = blockIdx.y;  // 0..7
  const int b = blockIdx.z;

  int pos = blockIdx.x * 256 + tid;
  bool valid = pos < 6561;
  int p = valid ? pos : 6560;
  int d1 = p / 729, r = p % 729;
  int d2 = r / 81;
  r %= 81;
  int d3 = r / 9, d4 = r % 9;

  float2 acc[8];
#pragma unroll
  for (int u = 0; u < 8; ++u) acc[u] = make_float2(0.f, 0.f);

  const float* xrb = xr + b * 32 * 6561;
  const float* xib = xi + b * 32 * 6561;
  const int wbase = cg * 81 * 512;

  for (int t = 0; t < 81; ++t) {
    __syncthreads();  // protect previous tap's lw reads
    lw[tid] = wt[wbase + t * 512 + tid];
    lw[tid + 256] = wt[wbase + t * 512 + tid + 256];
    __syncthreads();

    int j1 = t / 27, j2 = (t / 9) % 3, j3 = (t / 3) % 3, j4 = t % 3;
    int e1 = d1 + j1 - 1, e2 = d2 + j2 - 1, e3 = d3 + j3 - 1, e4 = d4 + j4 - 1;
    bool ok = ((unsigned)e1 < 9u) & ((unsigned)e2 < 9u) & ((unsigned)e3 < 9u) &
              ((unsigned)e4 < 9u);
    if (!ok) continue;  // next barrier is at top of next iteration: uniform
    int off = ((e1 * 9 + e2) * 9 + e3) * 9 + e4;
    const float4* lwv = (const float4*)lw;
    for (int ci = 0; ci < 32; ++ci) {
      float xrv = xrb[ci * 6561 + off];
      float xiv = xib[ci * 6561 + off];
#pragma unroll
      for (int u4 = 0; u4 < 4; ++u4) {
        float4 w = lwv[ci * 4 + u4];  // wr(2u4), wi(2u4), wr(2u4+1), wi(2u4+1)
        acc[2 * u4].x += xrv * w.x - xiv * w.y;
        acc[2 * u4].y += xrv * w.y + xiv * w.x;
        acc[2 * u4 + 1].x += xrv * w.z - xiv * w.w;
        acc[2 * u4 + 1].y += xrv * w.w + xiv * w.z;
      }
    }
  }

  if (valid) {
#pragma unroll
    for (int u = 0; u < 8; ++u) {
      int co = cg * 8 + u;
      float vr = fmaxf(acc[u].x + br[co], 0.f);
      float vi = fmaxf(acc[u].y + bi[co], 0.f);
      yr[(b * 64 + co) * 6561 + p] = vr;
      yi[(b * 64 + co) * 6561 + p] = vi;
    }
  }
}

// ---- 1x1 complex conv (layers 3,4,5). 8 co per block. ----------------------
__global__ __launch_bounds__(256) void cconv1x1(
    const float* __restrict__ xr, const float* __restrict__ xi,
    const float* __restrict__ wt, const float* __restrict__ br,
    const float* __restrict__ bi, float* __restrict__ yr,
    float* __restrict__ yi, int Cin, int Cout, int npos_out, int stride) {
  __shared__ __align__(16) float lw[2048];  // [ci][u=8][ri=2], Cin<=128
  const int tid = threadIdx.x;
  const int cg = blockIdx.y;
  const int b = blockIdx.z;
  const int nstage = Cin * 16;
  for (int i = tid; i < nstage; i += 256) lw[i] = wt[cg * nstage + i];
  __syncthreads();

  int pos = blockIdx.x * 256 + tid;
  bool valid = pos < npos_out;
  int p = valid ? pos : npos_out - 1;
  int off;
  if (stride == 2) {
    int d1 = p / 125, r = p % 125;
    int d2 = r / 25;
    r %= 25;
    int d3 = r / 5, d4 = r % 5;
    off = (2 * d1) * 729 + (2 * d2) * 81 + (2 * d3) * 9 + 2 * d4;
  } else {
    off = p;
  }
  const float* xrb = xr + b * Cin * 6561 + off;
  const float* xib = xi + b * Cin * 6561 + off;

  float2 acc[8];
#pragma unroll
  for (int u = 0; u < 8; ++u) acc[u] = make_float2(0.f, 0.f);

  const float4* lwv = (const float4*)lw;
  for (int ci = 0; ci < Cin; ++ci) {
    float xrv = xrb[ci * 6561];
    float xiv = xib[ci * 6561];
#pragma unroll
    for (int u4 = 0; u4 < 4; ++u4) {
      float4 w = lwv[ci * 4 + u4];
      acc[2 * u4].x += xrv * w.x - xiv * w.y;
      acc[2 * u4].y += xrv * w.y + xiv * w.x;
      acc[2 * u4 + 1].x += xrv * w.z - xiv * w.w;
      acc[2 * u4 + 1].y += xrv * w.w + xiv * w.z;
    }
  }

  if (valid) {
#pragma unroll
    for (int u = 0; u < 8; ++u) {
      int co = cg * 8 + u;
      float vr = fmaxf(acc[u].x + br[co], 0.f);
      float vi = fmaxf(acc[u].y + bi[co], 0.f);
      yr[(b * Cout + co) * npos_out + p] = vr;
      yi[(b * Cout + co) * npos_out + p] = vi;
    }
  }
}

// ---- FC: out[bc] = sum_p o5r[bc,p]*fcw[p] + fcb ; out[256+bc] = i-part -----
__global__ __launch_bounds__(64) void fc_kernel(
    const float* __restrict__ o5r, const float* __restrict__ o5i,
    const float* __restrict__ fcw, const float* __restrict__ fcb,
    float* __restrict__ out) {
  int bc = blockIdx.x;   // b*64 + c, 0..255
  int lane = threadIdx.x;
  const float* pr = o5r + bc * 625;
  const float* pi = o5i + bc * 625;
  float sr = 0.f, si = 0.f;
  for (int k = lane; k < 625; k += 64) {
    float w = fcw[k];
    sr += fmaxf(pr[k], 0.f) * w;  // relu idempotent (already applied)
    si += fmaxf(pi[k], 0.f) * w;
  }
#pragma unroll
  for (int s = 32; s > 0; s >>= 1) {
    sr += __shfl_down(sr, s);
    si += __shfl_down(si, s);
  }
  if (lane == 0) {
    out[bc] = sr + fcb[0];
    out[256 + bc] = si;
  }
}

extern "C" void kernel_launch(void* const* d_in, const int* in_sizes, int n_in,
                              void* d_out, int out_size, void* d_ws,
                              size_t ws_size, hipStream_t stream) {
  const float* xr = (const float*)d_in[0];
  const float* xi = (const float*)d_in[1];
  const float* w1r = (const float*)d_in[2];
  const float* w1i = (const float*)d_in[3];
  const float* b1r = (const float*)d_in[4];
  const float* b1i = (const float*)d_in[5];
  const float* w2r = (const float*)d_in[6];
  const float* w2i = (const float*)d_in[7];
  const float* b2r = (const float*)d_in[8];
  const float* b2i = (const float*)d_in[9];
  const float* w3r = (const float*)d_in[10];
  const float* w3i = (const float*)d_in[11];
  const float* b3r = (const float*)d_in[12];
  const float* b3i = (const float*)d_in[13];
  const float* w4r = (const float*)d_in[14];
  const float* w4i = (const float*)d_in[15];
  const float* b4r = (const float*)d_in[16];
  const float* b4i = (const float*)d_in[17];
  const float* w5r = (const float*)d_in[18];
  const float* w5i = (const float*)d_in[19];
  const float* b5r = (const float*)d_in[20];
  const float* b5i = (const float*)d_in[21];
  const float* fcw = (const float*)d_in[22];
  const float* fcb = (const float*)d_in[23];
  float* out = (float*)d_out;

  float* ws = (float*)d_ws;
  // transposed weights
  float* wt1 = ws;              // 32*1*81*2      = 5184
  float* wt2 = ws + 5184;       // 64*32*81*2     = 331776
  float* wt3 = ws + 336960;     // 128*64*2       = 16384
  float* wt4 = ws + 353344;     // 128*128*2      = 32768
  float* wt5 = ws + 386112;     // 64*128*2       = 16384
  // ping-pong activation buffers, each 6,718,464 floats (fits o3/o4)
  float* bufA = ws + 402496;
  float* bufB = bufA + 6718464;
  // A: o1 (2*839808), then o3 (2*3359232), then o5 (2*160000)
  float* o1r = bufA;
  float* o1i = bufA + 839808;
  float* o3r = bufA;
  float* o3i = bufA + 3359232;
  float* o5r = bufA;
  float* o5i = bufA + 160000;
  // B: o2 (2*1679616), then o4 (2*3359232)
  float* o2r = bufB;
  float* o2i = bufB + 1679616;
  float* o4r = bufB;
  float* o4i = bufB + 3359232;

  // weight transposes (tiny; deterministic every call)
  transpose_w_kernel<<<dim3(16), 256, 0, stream>>>(w1r, w1i, wt1, 32, 1, 81, 16);
  transpose_w_kernel<<<dim3(256), 256, 0, stream>>>(w2r, w2i, wt2, 64, 32, 81, 8);
  transpose_w_kernel<<<dim3(32), 256, 0, stream>>>(w3r, w3i, wt3, 128, 64, 1, 8);
  transpose_w_kernel<<<dim3(64), 256, 0, stream>>>(w4r, w4i, wt4, 128, 128, 1, 8);
  transpose_w_kernel<<<dim3(32), 256, 0, stream>>>(w5r, w5i, wt5, 64, 128, 1, 8);

  cconv_l1<<<dim3(26, 2, 4), 256, 0, stream>>>(xr, xi, wt1, b1r, b1i, o1r, o1i);
  cconv_k3<<<dim3(26, 8, 4), 256, 0, stream>>>(o1r, o1i, wt2, b2r, b2i, o2r, o2i);
  cconv1x1<<<dim3(26, 16, 4), 256, 0, stream>>>(o2r, o2i, wt3, b3r, b3i, o3r,
                                                o3i, 64, 128, 6561, 1);
  cconv1x1<<<dim3(26, 16, 4), 256, 0, stream>>>(o3r, o3i, wt4, b4r, b4i, o4r,
                                                o4i, 128, 128, 6561, 1);
  cconv1x1<<<dim3(3, 8, 4), 256, 0, stream>>>(o4r, o4i, wt5, b5r, b5i, o5r,
                                              o5i, 128, 64, 625, 2);
  fc_kernel<<<dim3(256), 64, 0, stream>>>(o5r, o5i, fcw, fcb, out);
}

// Round 2
// 333.873 us; speedup vs baseline: 3.6832x; 3.6832x over previous
//
#include <hip/hip_runtime.h>
#include <hip/hip_bf16.h>

typedef __bf16 bf16x8v __attribute__((ext_vector_type(8)));
typedef float f32x4 __attribute__((ext_vector_type(4)));

#define GLD16(gp, loff)                                                     \
  __builtin_amdgcn_global_load_lds(                                         \
      (const __attribute__((address_space(1))) void*)(gp),                  \
      (__attribute__((address_space(3))) void*)(smem + (loff)), 16, 0, 0)

// ---------------------------------------------------------------------------
// Layout notes:
//  xp: padded bf16 channel-last L1 output: [b][q:11^4][c'=64] (c'=ci real,
//      32+ci imag), zero halo. q(d,j) = q00(d) + delta(j), always in-bounds.
//  wt2b: bf16 B-matrices per tap, [t:81][n:128][k:64] row-major (n-major so
//      MFMA B-frag reads 8 contiguous k): n<64 real col, n>=64 imag col.
//  o2..o5: fp32 planes [b][c][pos] (r and i separate), as in round 1.
// ---------------------------------------------------------------------------

__global__ __launch_bounds__(256) void zero_u4(uint4* p, int n16) {
  int i = blockIdx.x * 256 + threadIdx.x;
  if (i < n16) p[i] = make_uint4(0, 0, 0, 0);
}

__global__ __launch_bounds__(256) void transpose_w_kernel(
    const float* __restrict__ wr, const float* __restrict__ wi,
    float* __restrict__ dst, int Cout, int Cin, int T, int G) {
  int n = Cout * Cin * T;
  for (int idx = blockIdx.x * blockDim.x + threadIdx.x; idx < n;
       idx += gridDim.x * blockDim.x) {
    int t = idx % T;
    int ci = (idx / T) % Cin;
    int co = idx / (T * Cin);
    int cg = co / G, u = co % G;
    int d = ((((cg * T + t) * Cin) + ci) * G + u) * 2;
    dst[d] = wr[idx];
    dst[d + 1] = wi[idx];
  }
}

// Build B[t][n][k] bf16 for L2 from w2r/w2i [co][ci][t].
__global__ __launch_bounds__(256) void pack_w2(
    const float* __restrict__ wr, const float* __restrict__ wi,
    __hip_bfloat16* __restrict__ dst) {
  int idx = blockIdx.x * 256 + threadIdx.x;  // t*8192 + n*64 + k
  if (idx >= 81 * 128 * 64) return;
  int k = idx & 63, n = (idx >> 6) & 127, t = idx >> 13;
  int ci = k & 31, kin_i = k >> 5;  // 0: pairs with xr rows, 1: xi rows
  int co = n & 63, out_i = n >> 6;  // 0: yr col, 1: yi col
  int widx = (co * 32 + ci) * 81 + t;
  float v;
  if (out_i == 0) v = (kin_i == 0) ? wr[widx] : -wi[widx];
  else            v = (kin_i == 0) ? wi[widx] :  wr[widx];
  dst[idx] = __float2bfloat16(v);
}

// ---- Layer 1: Cin=1, Cout=32 (16/block), k=3, s=2, in 20^4 -> padded xp ----
__global__ __launch_bounds__(256) void cconv_l1(
    const float* __restrict__ xr, const float* __restrict__ xi,
    const float* __restrict__ wt, const float* __restrict__ br,
    const float* __restrict__ bi, __hip_bfloat16* __restrict__ xp) {
  __shared__ __align__(16) float lw[81 * 16 * 2];  // [t][u][ri]
  const int tid = threadIdx.x;
  const int cg = blockIdx.y;  // 0..1 -> co = cg*16+u
  const int b = blockIdx.z;
  for (int i = tid; i < 2592; i += 256) lw[i] = wt[cg * 2592 + i];
  __syncthreads();

  int pos = blockIdx.x * 256 + tid;
  bool valid = pos < 6561;
  int p = valid ? pos : 6560;
  int d1 = p / 729, r = p % 729;
  int d2 = r / 81;
  r %= 81;
  int d3 = r / 9, d4 = r % 9;
  const int base = b * 160000 + d1 * 16000 + d2 * 800 + d3 * 40 + d4 * 2;
  const float* xrb = xr + base;
  const float* xib = xi + base;

  float2 acc[16];
#pragma unroll
  for (int u = 0; u < 16; ++u) acc[u] = make_float2(0.f, 0.f);

  for (int j1 = 0; j1 < 3; ++j1)
    for (int j2 = 0; j2 < 3; ++j2)
      for (int j3 = 0; j3 < 3; ++j3)
#pragma unroll
        for (int j4 = 0; j4 < 3; ++j4) {
          int t = ((j1 * 3 + j2) * 3 + j3) * 3 + j4;
          int xo = j1 * 8000 + j2 * 400 + j3 * 20 + j4;
          float xrv = xrb[xo], xiv = xib[xo];
          const float2* wv = (const float2*)&lw[t * 32];
#pragma unroll
          for (int u = 0; u < 16; ++u) {
            float2 w = wv[u];
            acc[u].x += xrv * w.x - xiv * w.y;
            acc[u].y += xrv * w.y + xiv * w.x;
          }
        }

  if (valid) {
    int q = (((d1 + 1) * 11 + (d2 + 1)) * 11 + (d3 + 1)) * 11 + (d4 + 1);
    __hip_bfloat16* xq = xp + ((size_t)(b * 14641 + q)) * 64 + cg * 16;
#pragma unroll
    for (int u = 0; u < 16; ++u) {
      int co = cg * 16 + u;
      xq[u] = __float2bfloat16(fmaxf(acc[u].x + br[co], 0.f));
      xq[32 + u] = __float2bfloat16(fmaxf(acc[u].y + bi[co], 0.f));
    }
  }
}

// ---- Layer 2: implicit-GEMM MFMA. M=128 pos, N=128 (yr|yi), K=64 per tap,
//      81 taps accumulated. 4 waves, wave tile 64x64, double-buffered LDS. ---
__global__ __launch_bounds__(256) void cconv2_mfma(
    const __hip_bfloat16* __restrict__ xp, const __hip_bfloat16* __restrict__ wb,
    const float* __restrict__ br, const float* __restrict__ bi,
    float* __restrict__ yr, float* __restrict__ yi) {
  __shared__ __align__(128) char smem[65536];  // 2 x (A 16KB + B 16KB)
  const int tid = threadIdx.x;
  const int l = tid & 63, w = tid >> 6;
  const int wm = w >> 1, wn = w & 1;
  const int b = blockIdx.y;
  const int p0 = blockIdx.x * 128;

  // --- staging constants (per thread) ---
  const int swz = ((l & 7) ^ (l >> 3)) << 4;      // 16B-slot XOR swizzle
  const char* xpB = (const char*)(xp + (size_t)b * 14641 * 64);
  const char* wB = (const char*)wb;
  int q00[4], rbB[4];
#pragma unroll
  for (int c = 0; c < 4; ++c) {
    int row = w * 32 + c * 8 + (l >> 3);
    int p = p0 + row;
    if (p > 6560) p = 6560;
    int d1 = p / 729, r = p % 729;
    int d2 = r / 81;
    r %= 81;
    int d3 = r / 9, d4 = r % 9;
    q00[c] = ((d1 * 11 + d2) * 11 + d3) * 11 + d4;
    rbB[c] = row * 128 + swz;
  }

  // --- fragment-read constants ---
  const int l15 = l & 15;
  const int klo = (l >> 4) << 4;       // 0,16,32,48 byte within k-run
  const int sx = (l & 7) << 4;         // read-side swizzle (row&7 == l&7)
  const int arow0 = (wm * 64 + l15) * 128;
  const int brow0 = 16384 + (wn * 64 + l15) * 128;

  f32x4 acc[4][4];
#pragma unroll
  for (int mi = 0; mi < 4; ++mi)
#pragma unroll
    for (int ni = 0; ni < 4; ++ni) acc[mi][ni] = (f32x4){0.f, 0.f, 0.f, 0.f};

  auto stage = [&](int t, int nb) {
    int j1 = t / 27, j2 = (t / 9) % 3, j3 = (t / 3) % 3, j4 = t % 3;
    int delta = ((j1 * 11 + j2) * 11 + j3) * 11 + j4;
#pragma unroll
    for (int c = 0; c < 4; ++c) {
      GLD16(xpB + (((size_t)(q00[c] + delta)) << 7) + swz,
            nb + w * 4096 + c * 1024);
      GLD16(wB + (((size_t)t) << 14) + rbB[c],
            nb + 16384 + w * 4096 + c * 1024);
    }
  };

  stage(0, 0);
  __syncthreads();

  int cur = 0;
  for (int t = 0; t < 81; ++t) {
    if (t < 80) stage(t + 1, (cur ^ 1) * 32768);
    const char* sb = smem + cur * 32768;
#pragma unroll
    for (int kh = 0; kh < 2; ++kh) {
      const int kx = ((kh << 6) + klo) ^ sx;
      bf16x8v af[4], bfr[4];
#pragma unroll
      for (int mi = 0; mi < 4; ++mi)
        af[mi] = *(const bf16x8v*)(sb + arow0 + mi * 2048 + kx);
#pragma unroll
      for (int ni = 0; ni < 4; ++ni)
        bfr[ni] = *(const bf16x8v*)(sb + brow0 + ni * 2048 + kx);
#pragma unroll
      for (int mi = 0; mi < 4; ++mi)
#pragma unroll
        for (int ni = 0; ni < 4; ++ni)
          acc[mi][ni] = __builtin_amdgcn_mfma_f32_16x16x32_bf16(
              af[mi], bfr[ni], acc[mi][ni], 0, 0, 0);
    }
    __syncthreads();  // drains vmcnt (next-tap stage) + lgkm (frag reads)
    cur ^= 1;
  }

  // --- epilogue: bias + CReLU, write fp32 planes ---
  const int prow = p0 + wm * 64 + ((l >> 4) << 2);
  const int col0 = wn * 64 + l15;
#pragma unroll
  for (int ni = 0; ni < 4; ++ni) {
    int cn = col0 + ni * 16;
    float bias = (cn < 64) ? br[cn] : bi[cn - 64];
    float* plane = (cn < 64) ? yr + ((size_t)(b * 64 + cn)) * 6561
                             : yi + ((size_t)(b * 64 + cn - 64)) * 6561;
#pragma unroll
    for (int mi = 0; mi < 4; ++mi)
#pragma unroll
      for (int j = 0; j < 4; ++j) {
        int p = prow + mi * 16 + j;
        if (p < 6561) plane[p] = fmaxf(acc[mi][ni][j] + bias, 0.f);
      }
  }
}

// ---- 1x1 complex conv (layers 3,4,5). 8 co per block. ----------------------
__global__ __launch_bounds__(256) void cconv1x1(
    const float* __restrict__ xr, const float* __restrict__ xi,
    const float* __restrict__ wt, const float* __restrict__ br,
    const float* __restrict__ bi, float* __restrict__ yr,
    float* __restrict__ yi, int Cin, int Cout, int npos_out, int stride) {
  __shared__ __align__(16) float lw[2048];  // [ci][u=8][ri=2], Cin<=128
  const int tid = threadIdx.x;
  const int cg = blockIdx.y;
  const int b = blockIdx.z;
  const int nstage = Cin * 16;
  for (int i = tid; i < nstage; i += 256) lw[i] = wt[cg * nstage + i];
  __syncthreads();

  int pos = blockIdx.x * 256 + tid;
  bool valid = pos < npos_out;
  int p = valid ? pos : npos_out - 1;
  int off;
  if (stride == 2) {
    int d1 = p / 125, r = p % 125;
    int d2 = r / 25;
    r %= 25;
    int d3 = r / 5, d4 = r % 5;
    off = (2 * d1) * 729 + (2 * d2) * 81 + (2 * d3) * 9 + 2 * d4;
  } else {
    off = p;
  }
  const float* xrb = xr + b * Cin * 6561 + off;
  const float* xib = xi + b * Cin * 6561 + off;

  float2 acc[8];
#pragma unroll
  for (int u = 0; u < 8; ++u) acc[u] = make_float2(0.f, 0.f);

  const float4* lwv = (const float4*)lw;
  for (int ci = 0; ci < Cin; ++ci) {
    float xrv = xrb[ci * 6561];
    float xiv = xib[ci * 6561];
#pragma unroll
    for (int u4 = 0; u4 < 4; ++u4) {
      float4 w = lwv[ci * 4 + u4];
      acc[2 * u4].x += xrv * w.x - xiv * w.y;
      acc[2 * u4].y += xrv * w.y + xiv * w.x;
      acc[2 * u4 + 1].x += xrv * w.z - xiv * w.w;
      acc[2 * u4 + 1].y += xrv * w.w + xiv * w.z;
    }
  }

  if (valid) {
#pragma unroll
    for (int u = 0; u < 8; ++u) {
      int co = cg * 8 + u;
      float vr = fmaxf(acc[u].x + br[co], 0.f);
      float vi = fmaxf(acc[u].y + bi[co], 0.f);
      yr[(b * Cout + co) * npos_out + p] = vr;
      yi[(b * Cout + co) * npos_out + p] = vi;
    }
  }
}

// ---- FC ------------------------------------------------------------------
__global__ __launch_bounds__(64) void fc_kernel(
    const float* __restrict__ o5r, const float* __restrict__ o5i,
    const float* __restrict__ fcw, const float* __restrict__ fcb,
    float* __restrict__ out) {
  int bc = blockIdx.x;  // b*64 + c
  int lane = threadIdx.x;
  const float* pr = o5r + bc * 625;
  const float* pi = o5i + bc * 625;
  float sr = 0.f, si = 0.f;
  for (int k = lane; k < 625; k += 64) {
    float w = fcw[k];
    sr += fmaxf(pr[k], 0.f) * w;
    si += fmaxf(pi[k], 0.f) * w;
  }
#pragma unroll
  for (int s = 32; s > 0; s >>= 1) {
    sr += __shfl_down(sr, s);
    si += __shfl_down(si, s);
  }
  if (lane == 0) {
    out[bc] = sr + fcb[0];
    out[256 + bc] = si;
  }
}

extern "C" void kernel_launch(void* const* d_in, const int* in_sizes, int n_in,
                              void* d_out, int out_size, void* d_ws,
                              size_t ws_size, hipStream_t stream) {
  const float* xr = (const float*)d_in[0];
  const float* xi = (const float*)d_in[1];
  const float* w1r = (const float*)d_in[2];
  const float* w1i = (const float*)d_in[3];
  const float* b1r = (const float*)d_in[4];
  const float* b1i = (const float*)d_in[5];
  const float* w2r = (const float*)d_in[6];
  const float* w2i = (const float*)d_in[7];
  const float* b2r = (const float*)d_in[8];
  const float* b2i = (const float*)d_in[9];
  const float* w3r = (const float*)d_in[10];
  const float* w3i = (const float*)d_in[11];
  const float* b3r = (const float*)d_in[12];
  const float* b3i = (const float*)d_in[13];
  const float* w4r = (const float*)d_in[14];
  const float* w4i = (const float*)d_in[15];
  const float* b4r = (const float*)d_in[16];
  const float* b4i = (const float*)d_in[17];
  const float* w5r = (const float*)d_in[18];
  const float* w5i = (const float*)d_in[19];
  const float* b5r = (const float*)d_in[20];
  const float* b5i = (const float*)d_in[21];
  const float* fcw = (const float*)d_in[22];
  const float* fcb = (const float*)d_in[23];
  float* out = (float*)d_out;

  float* ws = (float*)d_ws;
  float* wt1 = ws;                       // 5184
  float* wt3 = ws + 5184;                // 16384
  float* wt4 = ws + 21568;               // 32768
  float* wt5 = ws + 54336;               // 16384
  __hip_bfloat16* wt2b = (__hip_bfloat16*)(ws + 70720);  // 663552 bf16
  float* bufA = ws + 402496;             // 6718464 floats
  float* bufB = bufA + 6718464;          // 6718464 floats

  // bufA: xp (bf16, 3748096 elems) -> then o3 -> then o5
  __hip_bfloat16* xp = (__hip_bfloat16*)bufA;
  float* o3r = bufA;
  float* o3i = bufA + 3359232;
  float* o5r = bufA;
  float* o5i = bufA + 160000;
  // bufB: o2 -> o4
  float* o2r = bufB;
  float* o2i = bufB + 1679616;
  float* o4r = bufB;
  float* o4i = bufB + 3359232;

  // prep
  zero_u4<<<dim3(1831), 256, 0, stream>>>((uint4*)xp, 468512);
  transpose_w_kernel<<<dim3(16), 256, 0, stream>>>(w1r, w1i, wt1, 32, 1, 81, 16);
  pack_w2<<<dim3(2592), 256, 0, stream>>>(w2r, w2i, wt2b);
  transpose_w_kernel<<<dim3(32), 256, 0, stream>>>(w3r, w3i, wt3, 128, 64, 1, 8);
  transpose_w_kernel<<<dim3(64), 256, 0, stream>>>(w4r, w4i, wt4, 128, 128, 1, 8);
  transpose_w_kernel<<<dim3(32), 256, 0, stream>>>(w5r, w5i, wt5, 64, 128, 1, 8);

  cconv_l1<<<dim3(26, 2, 4), 256, 0, stream>>>(xr, xi, wt1, b1r, b1i, xp);
  cconv2_mfma<<<dim3(52, 4), 256, 0, stream>>>(xp, wt2b, b2r, b2i, o2r, o2i);
  cconv1x1<<<dim3(26, 16, 4), 256, 0, stream>>>(o2r, o2i, wt3, b3r, b3i, o3r,
                                                o3i, 64, 128, 6561, 1);
  cconv1x1<<<dim3(26, 16, 4), 256, 0, stream>>>(o3r, o3i, wt4, b4r, b4i, o4r,
                                                o4i, 128, 128, 6561, 1);
  cconv1x1<<<dim3(3, 8, 4), 256, 0, stream>>>(o4r, o4i, wt5, b5r, b5i, o5r,
                                              o5i, 128, 64, 625, 2);
  fc_kernel<<<dim3(256), 64, 0, stream>>>(o5r, o5i, fcw, fcb, out);
}

// Round 3
// 178.461 us; speedup vs baseline: 6.8906x; 1.8708x over previous
//
#include <hip/hip_runtime.h>
#include <hip/hip_bf16.h>

typedef __bf16 bf16x8v __attribute__((ext_vector_type(8)));
typedef float f32x4 __attribute__((ext_vector_type(4)));

#define GLD16(gp, loff)                                                     \
  __builtin_amdgcn_global_load_lds(                                         \
      (const __attribute__((address_space(1))) void*)(gp),                  \
      (__attribute__((address_space(3))) void*)(smem + (loff)), 16, 0, 0)

// ---------------------------------------------------------------------------
// Pipeline (bf16 channel-last activations after L1):
//  xp : [b][q:11^4][64]  padded L1 out (32r|32i), zero halo
//  a2 : [b*6561][128]    L2 out (64r|64i)
//  a3 : [b*6561][256]    L3 out (128r|128i)
//  a4 : [b*6561][256]    L4 out
//  a5 : [b*625 ][128]    L5 out (stride-2 gather)
//  Weights realified bf16: B[n][k], n = out (r cols then i cols),
//  k = in (r rows then i rows):  [wr -wi; wi wr].
// ---------------------------------------------------------------------------

__global__ __launch_bounds__(256) void zero_u4(uint4* p, int n16) {
  int i = blockIdx.x * 256 + threadIdx.x;
  if (i < n16) p[i] = make_uint4(0, 0, 0, 0);
}

__global__ __launch_bounds__(256) void transpose_w_kernel(
    const float* __restrict__ wr, const float* __restrict__ wi,
    float* __restrict__ dst, int Cout, int Cin, int T, int G) {
  int n = Cout * Cin * T;
  for (int idx = blockIdx.x * blockDim.x + threadIdx.x; idx < n;
       idx += gridDim.x * blockDim.x) {
    int t = idx % T;
    int ci = (idx / T) % Cin;
    int co = idx / (T * Cin);
    int cg = co / G, u = co % G;
    int d = ((((cg * T + t) * Cin) + ci) * G + u) * 2;
    dst[d] = wr[idx];
    dst[d + 1] = wi[idx];
  }
}

// B[t][n:128][k:64] bf16 for L2 from w2r/w2i [co][ci][t].
__global__ __launch_bounds__(256) void pack_w2(
    const float* __restrict__ wr, const float* __restrict__ wi,
    __hip_bfloat16* __restrict__ dst) {
  int idx = blockIdx.x * 256 + threadIdx.x;  // t*8192 + n*64 + k
  if (idx >= 81 * 128 * 64) return;
  int k = idx & 63, n = (idx >> 6) & 127, t = idx >> 13;
  int ci = k & 31, kin_i = k >> 5;
  int co = n & 63, out_i = n >> 6;
  int widx = (co * 32 + ci) * 81 + t;
  float v;
  if (out_i == 0) v = (kin_i == 0) ? wr[widx] : -wi[widx];
  else            v = (kin_i == 0) ? wi[widx] :  wr[widx];
  dst[idx] = __float2bfloat16(v);
}

// Realified 1x1 weights: dst[n:2Cout][k:2Cin] from w[co][ci].
__global__ __launch_bounds__(256) void pack_w1x1(
    const float* __restrict__ wr, const float* __restrict__ wi,
    __hip_bfloat16* __restrict__ dst, int Cout, int Cin) {
  int idx = blockIdx.x * 256 + threadIdx.x;
  int k2 = 2 * Cin;
  if (idx >= 2 * Cout * k2) return;
  int k = idx % k2, n = idx / k2;
  int ci = (k < Cin) ? k : k - Cin;
  int co = (n < Cout) ? n : n - Cout;
  int widx = co * Cin + ci;
  float v;
  if (n < Cout) v = (k < Cin) ? wr[widx] : -wi[widx];
  else          v = (k < Cin) ? wi[widx] :  wr[widx];
  dst[idx] = __float2bfloat16(v);
}

// ---- Layer 1: Cin=1, Cout=32 (16/block), k=3, s=2, in 20^4 -> padded xp ----
__global__ __launch_bounds__(256) void cconv_l1(
    const float* __restrict__ xr, const float* __restrict__ xi,
    const float* __restrict__ wt, const float* __restrict__ br,
    const float* __restrict__ bi, __hip_bfloat16* __restrict__ xp) {
  __shared__ __align__(16) float lw[81 * 16 * 2];  // [t][u][ri]
  const int tid = threadIdx.x;
  const int cg = blockIdx.y;
  const int b = blockIdx.z;
  for (int i = tid; i < 2592; i += 256) lw[i] = wt[cg * 2592 + i];
  __syncthreads();

  int pos = blockIdx.x * 256 + tid;
  bool valid = pos < 6561;
  int p = valid ? pos : 6560;
  int d1 = p / 729, r = p % 729;
  int d2 = r / 81;
  r %= 81;
  int d3 = r / 9, d4 = r % 9;
  const int base = b * 160000 + d1 * 16000 + d2 * 800 + d3 * 40 + d4 * 2;
  const float* xrb = xr + base;
  const float* xib = xi + base;

  float2 acc[16];
#pragma unroll
  for (int u = 0; u < 16; ++u) acc[u] = make_float2(0.f, 0.f);

  for (int j1 = 0; j1 < 3; ++j1)
    for (int j2 = 0; j2 < 3; ++j2)
      for (int j3 = 0; j3 < 3; ++j3)
#pragma unroll
        for (int j4 = 0; j4 < 3; ++j4) {
          int t = ((j1 * 3 + j2) * 3 + j3) * 3 + j4;
          int xo = j1 * 8000 + j2 * 400 + j3 * 20 + j4;
          float xrv = xrb[xo], xiv = xib[xo];
          const float2* wv = (const float2*)&lw[t * 32];
#pragma unroll
          for (int u = 0; u < 16; ++u) {
            float2 w = wv[u];
            acc[u].x += xrv * w.x - xiv * w.y;
            acc[u].y += xrv * w.y + xiv * w.x;
          }
        }

  if (valid) {
    int q = (((d1 + 1) * 11 + (d2 + 1)) * 11 + (d3 + 1)) * 11 + (d4 + 1);
    __hip_bfloat16* xq = xp + ((size_t)(b * 14641 + q)) * 64 + cg * 16;
#pragma unroll
    for (int u = 0; u < 16; ++u) {
      int co = cg * 16 + u;
      xq[u] = __float2bfloat16(fmaxf(acc[u].x + br[co], 0.f));
      xq[32 + u] = __float2bfloat16(fmaxf(acc[u].y + bi[co], 0.f));
    }
  }
}

// ---- Layer 2: implicit-GEMM MFMA, out -> a2 bf16 channel-last --------------
__global__ __launch_bounds__(256) void cconv2_mfma(
    const __hip_bfloat16* __restrict__ xp, const __hip_bfloat16* __restrict__ wb,
    const float* __restrict__ br, const float* __restrict__ bi,
    __hip_bfloat16* __restrict__ a2) {
  __shared__ __align__(128) char smem[65536];  // 2 x (A 16KB + B 16KB)
  const int tid = threadIdx.x;
  const int l = tid & 63, w = tid >> 6;
  const int wm = w >> 1, wn = w & 1;
  const int b = blockIdx.y;
  const int p0 = blockIdx.x * 128;

  const int swz = ((l & 7) ^ (l >> 3)) << 4;
  const char* xpB = (const char*)(xp + (size_t)b * 14641 * 64);
  const char* wB = (const char*)wb;
  int q00[4], rbB[4];
#pragma unroll
  for (int c = 0; c < 4; ++c) {
    int row = w * 32 + c * 8 + (l >> 3);
    int p = p0 + row;
    if (p > 6560) p = 6560;
    int d1 = p / 729, r = p % 729;
    int d2 = r / 81;
    r %= 81;
    int d3 = r / 9, d4 = r % 9;
    q00[c] = ((d1 * 11 + d2) * 11 + d3) * 11 + d4;
    rbB[c] = row * 128 + swz;
  }

  const int l15 = l & 15;
  const int klo = (l >> 4) << 4;
  const int sx = (l & 7) << 4;
  const int arow0 = (wm * 64 + l15) * 128;
  const int brow0 = 16384 + (wn * 64 + l15) * 128;

  f32x4 acc[4][4];
#pragma unroll
  for (int mi = 0; mi < 4; ++mi)
#pragma unroll
    for (int ni = 0; ni < 4; ++ni) acc[mi][ni] = (f32x4){0.f, 0.f, 0.f, 0.f};

  auto stage = [&](int t, int nb) {
    int j1 = t / 27, j2 = (t / 9) % 3, j3 = (t / 3) % 3, j4 = t % 3;
    int delta = ((j1 * 11 + j2) * 11 + j3) * 11 + j4;
#pragma unroll
    for (int c = 0; c < 4; ++c) {
      GLD16(xpB + (((size_t)(q00[c] + delta)) << 7) + swz,
            nb + w * 4096 + c * 1024);
      GLD16(wB + (((size_t)t) << 14) + rbB[c],
            nb + 16384 + w * 4096 + c * 1024);
    }
  };

  stage(0, 0);
  __syncthreads();

  int cur = 0;
  for (int t = 0; t < 81; ++t) {
    if (t < 80) stage(t + 1, (cur ^ 1) * 32768);
    const char* sb = smem + cur * 32768;
#pragma unroll
    for (int kh = 0; kh < 2; ++kh) {
      const int kx = ((kh << 6) + klo) ^ sx;
      bf16x8v af[4], bfr[4];
#pragma unroll
      for (int mi = 0; mi < 4; ++mi)
        af[mi] = *(const bf16x8v*)(sb + arow0 + mi * 2048 + kx);
#pragma unroll
      for (int ni = 0; ni < 4; ++ni)
        bfr[ni] = *(const bf16x8v*)(sb + brow0 + ni * 2048 + kx);
#pragma unroll
      for (int mi = 0; mi < 4; ++mi)
#pragma unroll
        for (int ni = 0; ni < 4; ++ni)
          acc[mi][ni] = __builtin_amdgcn_mfma_f32_16x16x32_bf16(
              af[mi], bfr[ni], acc[mi][ni], 0, 0, 0);
    }
    __syncthreads();
    cur ^= 1;
  }

  const int prow = p0 + wm * 64 + ((l >> 4) << 2);
  const int col0 = wn * 64 + l15;
#pragma unroll
  for (int ni = 0; ni < 4; ++ni) {
    int cn = col0 + ni * 16;
    float bias = (cn < 64) ? br[cn] : bi[cn - 64];
#pragma unroll
    for (int mi = 0; mi < 4; ++mi)
#pragma unroll
      for (int j = 0; j < 4; ++j) {
        int p = prow + mi * 16 + j;
        if (p < 6561)
          a2[((size_t)(b * 6561 + p)) * 128 + cn] =
              __float2bfloat16(fmaxf(acc[mi][ni][j] + bias, 0.f));
      }
  }
}

// ---- Generic bf16 GEMM: C[M][N] = relu(A[M][K] * B[N][K]^T + bias) ---------
// stride2: A rows gathered (L5). 128x128 tile, BK=64, double-buffered.
__global__ __launch_bounds__(256) void gemm_bf16(
    const __hip_bfloat16* __restrict__ A, const __hip_bfloat16* __restrict__ Bm,
    const float* __restrict__ br, const float* __restrict__ bi,
    __hip_bfloat16* __restrict__ C, int M, int N, int K, int Cout,
    int stride2) {
  __shared__ __align__(128) char smem[65536];
  const int tid = threadIdx.x;
  const int l = tid & 63, w = tid >> 6;
  const int wm = w >> 1, wn = w & 1;
  const int p0 = blockIdx.x * 128;
  const int n0 = blockIdx.y * 128;
  const int nk = K >> 6;

  const int swz = ((l & 7) ^ (l >> 3)) << 4;
  const char* aB = (const char*)A;
  const char* bB = (const char*)Bm;
  size_t ofsA[4], ofsB[4];
#pragma unroll
  for (int c = 0; c < 4; ++c) {
    int row = w * 32 + c * 8 + (l >> 3);
    int m = p0 + row;
    if (m >= M) m = M - 1;
    int srcrow;
    if (stride2) {
      int bb = m / 625, r = m % 625;
      int d1 = r / 125;
      r %= 125;
      int d2 = r / 25;
      r %= 25;
      int d3 = r / 5, d4 = r % 5;
      srcrow = bb * 6561 + d1 * 1458 + d2 * 162 + d3 * 18 + d4 * 2;
    } else {
      srcrow = m;
    }
    ofsA[c] = (size_t)srcrow * (2 * K) + swz;
    ofsB[c] = (size_t)(n0 + row) * (2 * K) + swz;
  }

  const int l15 = l & 15;
  const int klo = (l >> 4) << 4;
  const int sx = (l & 7) << 4;
  const int arow0 = (wm * 64 + l15) * 128;
  const int brow0 = 16384 + (wn * 64 + l15) * 128;

  f32x4 acc[4][4];
#pragma unroll
  for (int mi = 0; mi < 4; ++mi)
#pragma unroll
    for (int ni = 0; ni < 4; ++ni) acc[mi][ni] = (f32x4){0.f, 0.f, 0.f, 0.f};

  auto stage = [&](int kt, int nb) {
#pragma unroll
    for (int c = 0; c < 4; ++c) {
      GLD16(aB + ofsA[c] + kt * 128, nb + w * 4096 + c * 1024);
      GLD16(bB + ofsB[c] + kt * 128, nb + 16384 + w * 4096 + c * 1024);
    }
  };

  stage(0, 0);
  __syncthreads();

  int cur = 0;
  for (int kt = 0; kt < nk; ++kt) {
    if (kt + 1 < nk) stage(kt + 1, (cur ^ 1) * 32768);
    const char* sb = smem + cur * 32768;
#pragma unroll
    for (int kh = 0; kh < 2; ++kh) {
      const int kx = ((kh << 6) + klo) ^ sx;
      bf16x8v af[4], bfr[4];
#pragma unroll
      for (int mi = 0; mi < 4; ++mi)
        af[mi] = *(const bf16x8v*)(sb + arow0 + mi * 2048 + kx);
#pragma unroll
      for (int ni = 0; ni < 4; ++ni)
        bfr[ni] = *(const bf16x8v*)(sb + brow0 + ni * 2048 + kx);
#pragma unroll
      for (int mi = 0; mi < 4; ++mi)
#pragma unroll
        for (int ni = 0; ni < 4; ++ni)
          acc[mi][ni] = __builtin_amdgcn_mfma_f32_16x16x32_bf16(
              af[mi], bfr[ni], acc[mi][ni], 0, 0, 0);
    }
    __syncthreads();
    cur ^= 1;
  }

  const int prow = p0 + wm * 64 + ((l >> 4) << 2);
  const int col0 = n0 + wn * 64 + l15;
#pragma unroll
  for (int ni = 0; ni < 4; ++ni) {
    int cn = col0 + ni * 16;
    float bias = (cn < Cout) ? br[cn] : bi[cn - Cout];
#pragma unroll
    for (int mi = 0; mi < 4; ++mi)
#pragma unroll
      for (int j = 0; j < 4; ++j) {
        int m = prow + mi * 16 + j;
        if (m < M)
          C[(size_t)m * N + cn] =
              __float2bfloat16(fmaxf(acc[mi][ni][j] + bias, 0.f));
      }
  }
}

// ---- FC: out[b*64+c] = sum_p a5[(b*625+p)][c] * fcw[p] (+fcb real) ---------
__global__ __launch_bounds__(64) void fc_kernel(
    const __hip_bfloat16* __restrict__ a5, const float* __restrict__ fcw,
    const float* __restrict__ fcb, float* __restrict__ out) {
  int bc = blockIdx.x;
  int b = bc >> 6, c = bc & 63;
  int lane = threadIdx.x;
  const __hip_bfloat16* base = a5 + (size_t)b * 625 * 128;
  float sr = 0.f, si = 0.f;
  for (int p = lane; p < 625; p += 64) {
    float wv = fcw[p];
    sr += __bfloat162float(base[(size_t)p * 128 + c]) * wv;
    si += __bfloat162float(base[(size_t)p * 128 + 64 + c]) * wv;
  }
#pragma unroll
  for (int s = 32; s > 0; s >>= 1) {
    sr += __shfl_down(sr, s);
    si += __shfl_down(si, s);
  }
  if (lane == 0) {
    out[bc] = sr + fcb[0];
    out[256 + bc] = si;
  }
}

extern "C" void kernel_launch(void* const* d_in, const int* in_sizes, int n_in,
                              void* d_out, int out_size, void* d_ws,
                              size_t ws_size, hipStream_t stream) {
  const float* xr = (const float*)d_in[0];
  const float* xi = (const float*)d_in[1];
  const float* w1r = (const float*)d_in[2];
  const float* w1i = (const float*)d_in[3];
  const float* b1r = (const float*)d_in[4];
  const float* b1i = (const float*)d_in[5];
  const float* w2r = (const float*)d_in[6];
  const float* w2i = (const float*)d_in[7];
  const float* b2r = (const float*)d_in[8];
  const float* b2i = (const float*)d_in[9];
  const float* w3r = (const float*)d_in[10];
  const float* w3i = (const float*)d_in[11];
  const float* b3r = (const float*)d_in[12];
  const float* b3i = (const float*)d_in[13];
  const float* w4r = (const float*)d_in[14];
  const float* w4i = (const float*)d_in[15];
  const float* b4r = (const float*)d_in[16];
  const float* b4i = (const float*)d_in[17];
  const float* w5r = (const float*)d_in[18];
  const float* w5i = (const float*)d_in[19];
  const float* b5r = (const float*)d_in[20];
  const float* b5i = (const float*)d_in[21];
  const float* fcw = (const float*)d_in[22];
  const float* fcb = (const float*)d_in[23];
  float* out = (float*)d_out;

  float* ws = (float*)d_ws;
  float* wt1 = ws;                                        // 5184 f
  __hip_bfloat16* wt2b = (__hip_bfloat16*)(ws + 5184);    // 663552 bf16
  __hip_bfloat16* w3b = (__hip_bfloat16*)(ws + 336960);   // 32768 bf16
  __hip_bfloat16* w4b = (__hip_bfloat16*)(ws + 353344);   // 65536 bf16
  __hip_bfloat16* w5b = (__hip_bfloat16*)(ws + 386112);   // 32768 bf16
  __hip_bfloat16* xp = (__hip_bfloat16*)(ws + 402496);    // 3748096 bf16
  __hip_bfloat16* a2 = (__hip_bfloat16*)(ws + 2276544);   // 3359232 bf16
  __hip_bfloat16* a3 = (__hip_bfloat16*)(ws + 3956160);   // 6718464 bf16
  __hip_bfloat16* a4 = (__hip_bfloat16*)(ws + 7315392);   // 6718464 bf16
  __hip_bfloat16* a5 = (__hip_bfloat16*)(ws + 10674624);  // 320000 bf16

  zero_u4<<<dim3(1831), 256, 0, stream>>>((uint4*)xp, 468512);
  transpose_w_kernel<<<dim3(16), 256, 0, stream>>>(w1r, w1i, wt1, 32, 1, 81, 16);
  pack_w2<<<dim3(2592), 256, 0, stream>>>(w2r, w2i, wt2b);
  pack_w1x1<<<dim3(128), 256, 0, stream>>>(w3r, w3i, w3b, 128, 64);
  pack_w1x1<<<dim3(256), 256, 0, stream>>>(w4r, w4i, w4b, 128, 128);
  pack_w1x1<<<dim3(128), 256, 0, stream>>>(w5r, w5i, w5b, 64, 128);

  cconv_l1<<<dim3(26, 2, 4), 256, 0, stream>>>(xr, xi, wt1, b1r, b1i, xp);
  cconv2_mfma<<<dim3(52, 4), 256, 0, stream>>>(xp, wt2b, b2r, b2i, a2);
  gemm_bf16<<<dim3(206, 2), 256, 0, stream>>>(a2, w3b, b3r, b3i, a3, 26244,
                                              256, 128, 128, 0);
  gemm_bf16<<<dim3(206, 2), 256, 0, stream>>>(a3, w4b, b4r, b4i, a4, 26244,
                                              256, 256, 128, 0);
  gemm_bf16<<<dim3(20, 1), 256, 0, stream>>>(a4, w5b, b5r, b5i, a5, 2500, 128,
                                             256, 64, 1);
  fc_kernel<<<dim3(256), 64, 0, stream>>>(a5, fcw, fcb, out);
}

// Round 4
// 174.903 us; speedup vs baseline: 7.0308x; 1.0203x over previous
//
#include <hip/hip_runtime.h>
#include <hip/hip_bf16.h>

typedef __bf16 bf16x8v __attribute__((ext_vector_type(8)));
typedef float f32x4 __attribute__((ext_vector_type(4)));

#define GLD16(gp, loff)                                                     \
  __builtin_amdgcn_global_load_lds(                                         \
      (const __attribute__((address_space(1))) void*)(gp),                  \
      (__attribute__((address_space(3))) void*)(smem + (loff)), 16, 0, 0)

// ---------------------------------------------------------------------------
// Pipeline (bf16 channel-last activations after L1):
//  xp : [b][q:11^4][64]  padded L1 out (32r|32i), zero halo
//  a2 : [m:26244][128]   L2 out (64r|64i), m = b*6561+pos
//  a3/a4 : [m][256], a5 : [b*625][128]
//  Weights realified bf16: B[n][k] = [wr -wi; wi wr].
// ---------------------------------------------------------------------------

__global__ __launch_bounds__(256) void zero_u4(uint4* p, int n16) {
  int i = blockIdx.x * 256 + threadIdx.x;
  if (i < n16) p[i] = make_uint4(0, 0, 0, 0);
}

__global__ __launch_bounds__(256) void transpose_w_kernel(
    const float* __restrict__ wr, const float* __restrict__ wi,
    float* __restrict__ dst, int Cout, int Cin, int T, int G) {
  int n = Cout * Cin * T;
  for (int idx = blockIdx.x * blockDim.x + threadIdx.x; idx < n;
       idx += gridDim.x * blockDim.x) {
    int t = idx % T;
    int ci = (idx / T) % Cin;
    int co = idx / (T * Cin);
    int cg = co / G, u = co % G;
    int d = ((((cg * T + t) * Cin) + ci) * G + u) * 2;
    dst[d] = wr[idx];
    dst[d + 1] = wi[idx];
  }
}

__global__ __launch_bounds__(256) void pack_w2(
    const float* __restrict__ wr, const float* __restrict__ wi,
    __hip_bfloat16* __restrict__ dst) {
  int idx = blockIdx.x * 256 + threadIdx.x;  // t*8192 + n*64 + k
  if (idx >= 81 * 128 * 64) return;
  int k = idx & 63, n = (idx >> 6) & 127, t = idx >> 13;
  int ci = k & 31, kin_i = k >> 5;
  int co = n & 63, out_i = n >> 6;
  int widx = (co * 32 + ci) * 81 + t;
  float v;
  if (out_i == 0) v = (kin_i == 0) ? wr[widx] : -wi[widx];
  else            v = (kin_i == 0) ? wi[widx] :  wr[widx];
  dst[idx] = __float2bfloat16(v);
}

__global__ __launch_bounds__(256) void pack_w1x1(
    const float* __restrict__ wr, const float* __restrict__ wi,
    __hip_bfloat16* __restrict__ dst, int Cout, int Cin) {
  int idx = blockIdx.x * 256 + threadIdx.x;
  int k2 = 2 * Cin;
  if (idx >= 2 * Cout * k2) return;
  int k = idx % k2, n = idx / k2;
  int ci = (k < Cin) ? k : k - Cin;
  int co = (n < Cout) ? n : n - Cout;
  int widx = co * Cin + ci;
  float v;
  if (n < Cout) v = (k < Cin) ? wr[widx] : -wi[widx];
  else          v = (k < Cin) ? wi[widx] :  wr[widx];
  dst[idx] = __float2bfloat16(v);
}

__global__ __launch_bounds__(256) void cconv_l1(
    const float* __restrict__ xr, const float* __restrict__ xi,
    const float* __restrict__ wt, const float* __restrict__ br,
    const float* __restrict__ bi, __hip_bfloat16* __restrict__ xp) {
  __shared__ __align__(16) float lw[81 * 16 * 2];
  const int tid = threadIdx.x;
  const int cg = blockIdx.y;
  const int b = blockIdx.z;
  for (int i = tid; i < 2592; i += 256) lw[i] = wt[cg * 2592 + i];
  __syncthreads();

  int pos = blockIdx.x * 256 + tid;
  bool valid = pos < 6561;
  int p = valid ? pos : 6560;
  int d1 = p / 729, r = p % 729;
  int d2 = r / 81;
  r %= 81;
  int d3 = r / 9, d4 = r % 9;
  const int base = b * 160000 + d1 * 16000 + d2 * 800 + d3 * 40 + d4 * 2;
  const float* xrb = xr + base;
  const float* xib = xi + base;

  float2 acc[16];
#pragma unroll
  for (int u = 0; u < 16; ++u) acc[u] = make_float2(0.f, 0.f);

  for (int j1 = 0; j1 < 3; ++j1)
    for (int j2 = 0; j2 < 3; ++j2)
      for (int j3 = 0; j3 < 3; ++j3)
#pragma unroll
        for (int j4 = 0; j4 < 3; ++j4) {
          int t = ((j1 * 3 + j2) * 3 + j3) * 3 + j4;
          int xo = j1 * 8000 + j2 * 400 + j3 * 20 + j4;
          float xrv = xrb[xo], xiv = xib[xo];
          const float2* wv = (const float2*)&lw[t * 32];
#pragma unroll
          for (int u = 0; u < 16; ++u) {
            float2 w = wv[u];
            acc[u].x += xrv * w.x - xiv * w.y;
            acc[u].y += xrv * w.y + xiv * w.x;
          }
        }

  if (valid) {
    int q = (((d1 + 1) * 11 + (d2 + 1)) * 11 + (d3 + 1)) * 11 + (d4 + 1);
    __hip_bfloat16* xq = xp + ((size_t)(b * 14641 + q)) * 64 + cg * 16;
#pragma unroll
    for (int u = 0; u < 16; ++u) {
      int co = cg * 16 + u;
      xq[u] = __float2bfloat16(fmaxf(acc[u].x + br[co], 0.f));
      xq[32 + u] = __float2bfloat16(fmaxf(acc[u].y + bi[co], 0.f));
    }
  }
}

// ---- Layer 2: implicit-GEMM MFMA, 3-buffer stage-2-ahead counted vmcnt. ----
__global__ __launch_bounds__(256) void cconv2_mfma(
    const __hip_bfloat16* __restrict__ xp, const __hip_bfloat16* __restrict__ wb,
    const float* __restrict__ br, const float* __restrict__ bi,
    __hip_bfloat16* __restrict__ a2) {
  __shared__ __align__(128) char smem[98304];  // 3 x (A 16KB | B 16KB)
  const int tid = threadIdx.x;
  const int l = tid & 63, w = tid >> 6;
  const int wm = w >> 1, wn = w & 1;
  const int p0 = blockIdx.x * 128;

  const int swz = ((l & 7) ^ (l >> 3)) << 4;
  const char* xpB = (const char*)xp;
  const char* wB = (const char*)wb;
  int q00[4], rbB[4];
#pragma unroll
  for (int c = 0; c < 4; ++c) {
    int row = w * 32 + c * 8 + (l >> 3);
    int m = p0 + row;
    if (m > 26243) m = 26243;
    int b = m / 6561, p = m % 6561;
    int d1 = p / 729, r = p % 729;
    int d2 = r / 81;
    r %= 81;
    int d3 = r / 9, d4 = r % 9;
    q00[c] = b * 14641 + ((d1 * 11 + d2) * 11 + d3) * 11 + d4;
    rbB[c] = row * 128 + swz;
  }

  const int l15 = l & 15;
  const int klo = (l >> 4) << 4;
  const int sx = (l & 7) << 4;
  const int arow0 = (wm * 64 + l15) * 128;
  const int brow0 = 16384 + (wn * 64 + l15) * 128;

  f32x4 acc[4][4];
#pragma unroll
  for (int mi = 0; mi < 4; ++mi)
#pragma unroll
    for (int ni = 0; ni < 4; ++ni) acc[mi][ni] = (f32x4){0.f, 0.f, 0.f, 0.f};

  auto stage = [&](int t, int nb) {
    int j1 = t / 27, j2 = (t / 9) % 3, j3 = (t / 3) % 3, j4 = t % 3;
    int delta = ((j1 * 11 + j2) * 11 + j3) * 11 + j4;
#pragma unroll
    for (int c = 0; c < 4; ++c) {
      GLD16(xpB + (((size_t)(q00[c] + delta)) << 7) + swz,
            nb + w * 4096 + c * 1024);
      GLD16(wB + (((size_t)t) << 14) + rbB[c],
            nb + 16384 + w * 4096 + c * 1024);
    }
  };

  stage(0, 0);
  stage(1, 32768);

  int cur = 0;
  for (int t = 0; t < 81; ++t) {
    if (t < 80) {
      asm volatile("s_waitcnt vmcnt(8)" ::: "memory");
    } else {
      asm volatile("s_waitcnt vmcnt(0)" ::: "memory");
    }
    __builtin_amdgcn_s_barrier();
    if (t + 2 < 81) {
      int nb = cur + 2;
      if (nb >= 3) nb -= 3;
      stage(t + 2, nb * 32768);
    }
    const char* sb = smem + cur * 32768;
#pragma unroll
    for (int kh = 0; kh < 2; ++kh) {
      const int kx = ((kh << 6) + klo) ^ sx;
      bf16x8v af[4], bfr[4];
#pragma unroll
      for (int mi = 0; mi < 4; ++mi)
        af[mi] = *(const bf16x8v*)(sb + arow0 + mi * 2048 + kx);
#pragma unroll
      for (int ni = 0; ni < 4; ++ni)
        bfr[ni] = *(const bf16x8v*)(sb + brow0 + ni * 2048 + kx);
#pragma unroll
      for (int mi = 0; mi < 4; ++mi)
#pragma unroll
        for (int ni = 0; ni < 4; ++ni)
          acc[mi][ni] = __builtin_amdgcn_mfma_f32_16x16x32_bf16(
              af[mi], bfr[ni], acc[mi][ni], 0, 0, 0);
    }
    cur = (cur == 2) ? 0 : cur + 1;
  }

  const int prow = p0 + wm * 64 + ((l >> 4) << 2);
  const int col0 = wn * 64 + l15;
#pragma unroll
  for (int ni = 0; ni < 4; ++ni) {
    int cn = col0 + ni * 16;
    float bias = (cn < 64) ? br[cn] : bi[cn - 64];
#pragma unroll
    for (int mi = 0; mi < 4; ++mi)
#pragma unroll
      for (int j = 0; j < 4; ++j) {
        int m = prow + mi * 16 + j;
        if (m < 26244)
          a2[(size_t)m * 128 + cn] =
              __float2bfloat16(fmaxf(acc[mi][ni][j] + bias, 0.f));
      }
  }
}

// ---- Generic bf16 GEMM (2-buffer, unchanged) -------------------------------
__global__ __launch_bounds__(256) void gemm_bf16(
    const __hip_bfloat16* __restrict__ A, const __hip_bfloat16* __restrict__ Bm,
    const float* __restrict__ br, const float* __restrict__ bi,
    __hip_bfloat16* __restrict__ C, int M, int N, int K, int Cout,
    int stride2) {
  __shared__ __align__(128) char smem[65536];
  const int tid = threadIdx.x;
  const int l = tid & 63, w = tid >> 6;
  const int wm = w >> 1, wn = w & 1;
  const int p0 = blockIdx.x * 128;
  const int n0 = blockIdx.y * 128;
  const int nk = K >> 6;

  const int swz = ((l & 7) ^ (l >> 3)) << 4;
  const char* aB = (const char*)A;
  const char* bB = (const char*)Bm;
  size_t ofsA[4], ofsB[4];
#pragma unroll
  for (int c = 0; c < 4; ++c) {
    int row = w * 32 + c * 8 + (l >> 3);
    int m = p0 + row;
    if (m >= M) m = M - 1;
    int srcrow;
    if (stride2) {
      int bb = m / 625, r = m % 625;
      int d1 = r / 125;
      r %= 125;
      int d2 = r / 25;
      r %= 25;
      int d3 = r / 5, d4 = r % 5;
      srcrow = bb * 6561 + d1 * 1458 + d2 * 162 + d3 * 18 + d4 * 2;
    } else {
      srcrow = m;
    }
    ofsA[c] = (size_t)srcrow * (2 * K) + swz;
    ofsB[c] = (size_t)(n0 + row) * (2 * K) + swz;
  }

  const int l15 = l & 15;
  const int klo = (l >> 4) << 4;
  const int sx = (l & 7) << 4;
  const int arow0 = (wm * 64 + l15) * 128;
  const int brow0 = 16384 + (wn * 64 + l15) * 128;

  f32x4 acc[4][4];
#pragma unroll
  for (int mi = 0; mi < 4; ++mi)
#pragma unroll
    for (int ni = 0; ni < 4; ++ni) acc[mi][ni] = (f32x4){0.f, 0.f, 0.f, 0.f};

  auto stage = [&](int kt, int nb) {
#pragma unroll
    for (int c = 0; c < 4; ++c) {
      GLD16(aB + ofsA[c] + kt * 128, nb + w * 4096 + c * 1024);
      GLD16(bB + ofsB[c] + kt * 128, nb + 16384 + w * 4096 + c * 1024);
    }
  };

  stage(0, 0);
  __syncthreads();

  int cur = 0;
  for (int kt = 0; kt < nk; ++kt) {
    if (kt + 1 < nk) stage(kt + 1, (cur ^ 1) * 32768);
    const char* sb = smem + cur * 32768;
#pragma unroll
    for (int kh = 0; kh < 2; ++kh) {
      const int kx = ((kh << 6) + klo) ^ sx;
      bf16x8v af[4], bfr[4];
#pragma unroll
      for (int mi = 0; mi < 4; ++mi)
        af[mi] = *(const bf16x8v*)(sb + arow0 + mi * 2048 + kx);
#pragma unroll
      for (int ni = 0; ni < 4; ++ni)
        bfr[ni] = *(const bf16x8v*)(sb + brow0 + ni * 2048 + kx);
#pragma unroll
      for (int mi = 0; mi < 4; ++mi)
#pragma unroll
        for (int ni = 0; ni < 4; ++ni)
          acc[mi][ni] = __builtin_amdgcn_mfma_f32_16x16x32_bf16(
              af[mi], bfr[ni], acc[mi][ni], 0, 0, 0);
    }
    __syncthreads();
    cur ^= 1;
  }

  const int prow = p0 + wm * 64 + ((l >> 4) << 2);
  const int col0 = n0 + wn * 64 + l15;
#pragma unroll
  for (int ni = 0; ni < 4; ++ni) {
    int cn = col0 + ni * 16;
    float bias = (cn < Cout) ? br[cn] : bi[cn - Cout];
#pragma unroll
    for (int mi = 0; mi < 4; ++mi)
#pragma unroll
      for (int j = 0; j < 4; ++j) {
        int m = prow + mi * 16 + j;
        if (m < M)
          C[(size_t)m * N + cn] =
              __float2bfloat16(fmaxf(acc[mi][ni][j] + bias, 0.f));
      }
  }
}

__global__ __launch_bounds__(64) void fc_kernel(
    const __hip_bfloat16* __restrict__ a5, const float* __restrict__ fcw,
    const float* __restrict__ fcb, float* __restrict__ out) {
  int bc = blockIdx.x;
  int b = bc >> 6, c = bc & 63;
  int lane = threadIdx.x;
  const __hip_bfloat16* base = a5 + (size_t)b * 625 * 128;
  float sr = 0.f, si = 0.f;
  for (int p = lane; p < 625; p += 64) {
    float wv = fcw[p];
    sr += __bfloat162float(base[(size_t)p * 128 + c]) * wv;
    si += __bfloat162float(base[(size_t)p * 128 + 64 + c]) * wv;
  }
#pragma unroll
  for (int s = 32; s > 0; s >>= 1) {
    sr += __shfl_down(sr, s);
    si += __shfl_down(si, s);
  }
  if (lane == 0) {
    out[bc] = sr + fcb[0];
    out[256 + bc] = si;
  }
}

extern "C" void kernel_launch(void* const* d_in, const int* in_sizes, int n_in,
                              void* d_out, int out_size, void* d_ws,
                              size_t ws_size, hipStream_t stream) {
  const float* xr = (const float*)d_in[0];
  const float* xi = (const float*)d_in[1];
  const float* w1r = (const float*)d_in[2];
  const float* w1i = (const float*)d_in[3];
  const float* b1r = (const float*)d_in[4];
  const float* b1i = (const float*)d_in[5];
  const float* w2r = (const float*)d_in[6];
  const float* w2i = (const float*)d_in[7];
  const float* b2r = (const float*)d_in[8];
  const float* b2i = (const float*)d_in[9];
  const float* w3r = (const float*)d_in[10];
  const float* w3i = (const float*)d_in[11];
  const float* b3r = (const float*)d_in[12];
  const float* b3i = (const float*)d_in[13];
  const float* w4r = (const float*)d_in[14];
  const float* w4i = (const float*)d_in[15];
  const float* b4r = (const float*)d_in[16];
  const float* b4i = (const float*)d_in[17];
  const float* w5r = (const float*)d_in[18];
  const float* w5i = (const float*)d_in[19];
  const float* b5r = (const float*)d_in[20];
  const float* b5i = (const float*)d_in[21];
  const float* fcw = (const float*)d_in[22];
  const float* fcb = (const float*)d_in[23];
  float* out = (float*)d_out;

  float* ws = (float*)d_ws;
  float* wt1 = ws;                                        // 5184 f
  __hip_bfloat16* wt2b = (__hip_bfloat16*)(ws + 5184);    // 663552 bf16
  __hip_bfloat16* w3b = (__hip_bfloat16*)(ws + 336960);   // 32768 bf16
  __hip_bfloat16* w4b = (__hip_bfloat16*)(ws + 353344);   // 65536 bf16
  __hip_bfloat16* w5b = (__hip_bfloat16*)(ws + 386112);   // 32768 bf16
  __hip_bfloat16* xp = (__hip_bfloat16*)(ws + 402496);    // 3748096 bf16
  __hip_bfloat16* a2 = (__hip_bfloat16*)(ws + 2276544);   // 3359232 bf16
  __hip_bfloat16* a3 = (__hip_bfloat16*)(ws + 3956160);   // 6718464 bf16
  __hip_bfloat16* a4 = (__hip_bfloat16*)(ws + 7315392);   // 6718464 bf16
  __hip_bfloat16* a5 = (__hip_bfloat16*)(ws + 10674624);  // 320000 bf16

  zero_u4<<<dim3(1831), 256, 0, stream>>>((uint4*)xp, 468512);
  transpose_w_kernel<<<dim3(16), 256, 0, stream>>>(w1r, w1i, wt1, 32, 1, 81, 16);
  pack_w2<<<dim3(2592), 256, 0, stream>>>(w2r, w2i, wt2b);
  pack_w1x1<<<dim3(128), 256, 0, stream>>>(w3r, w3i, w3b, 128, 64);
  pack_w1x1<<<dim3(256), 256, 0, stream>>>(w4r, w4i, w4b, 128, 128);
  pack_w1x1<<<dim3(128), 256, 0, stream>>>(w5r, w5i, w5b, 64, 128);

  cconv_l1<<<dim3(26, 2, 4), 256, 0, stream>>>(xr, xi, wt1, b1r, b1i, xp);
  cconv2_mfma<<<dim3(206), 256, 0, stream>>>(xp, wt2b, b2r, b2i, a2);
  gemm_bf16<<<dim3(206, 2), 256, 0, stream>>>(a2, w3b, b3r, b3i, a3, 26244,
                                              256, 128, 128, 0);
  gemm_bf16<<<dim3(206, 2), 256, 0, stream>>>(a3, w4b, b4r, b4i, a4, 26244,
                                              256, 256, 128, 0);
  gemm_bf16<<<dim3(20, 1), 256, 0, stream>>>(a4, w5b, b5r, b5i, a5, 2500, 128,
                                             256, 64, 1);
  fc_kernel<<<dim3(256), 64, 0, stream>>>(a5, fcw, fcb, out);
}

// Round 5
// 147.471 us; speedup vs baseline: 8.3386x; 1.1860x over previous
//
#include <hip/hip_runtime.h>
#include <hip/hip_bf16.h>

typedef __bf16 bf16x8v __attribute__((ext_vector_type(8)));
typedef float f32x4 __attribute__((ext_vector_type(4)));

#define GLD16(gp, loff)                                                     \
  __builtin_amdgcn_global_load_lds(                                         \
      (const __attribute__((address_space(1))) void*)(gp),                  \
      (__attribute__((address_space(3))) void*)(smem + (loff)), 16, 0, 0)

// ---------------------------------------------------------------------------
// Pipeline (bf16 channel-last activations after L1):
//  xp : [b][q:11^4][64]  padded L1 out (32r|32i), zero halo
//  a2 : [m:26244][128]   L2 out (64r|64i), m = b*6561+pos
//  a3/a4 : [m][256], a5 : [b*625][128]
//  Weights realified bf16: B[n][k] = [wr -wi; wi wr].
// ---------------------------------------------------------------------------

// ---- fused prep: zero xp halo + all weight packs (one launch) --------------
__global__ __launch_bounds__(256) void prep_fused(
    const float* __restrict__ w1r, const float* __restrict__ w1i,
    const float* __restrict__ w2r, const float* __restrict__ w2i,
    const float* __restrict__ w3r, const float* __restrict__ w3i,
    const float* __restrict__ w4r, const float* __restrict__ w4i,
    const float* __restrict__ w5r, const float* __restrict__ w5i,
    float* __restrict__ wt1, __hip_bfloat16* __restrict__ wt2b,
    __hip_bfloat16* __restrict__ w3b, __hip_bfloat16* __restrict__ w4b,
    __hip_bfloat16* __restrict__ w5b, uint4* __restrict__ xpz) {
  const int bx = blockIdx.x;
  const int tid = threadIdx.x;
  auto pack11 = [](const float* wr, const float* wi, __hip_bfloat16* dst,
                   int Cout, int Cin, int idx) {
    int k2 = 2 * Cin;
    int k = idx % k2, n = idx / k2;
    int ci = (k < Cin) ? k : k - Cin;
    int co = (n < Cout) ? n : n - Cout;
    int widx = co * Cin + ci;
    float v;
    if (n < Cout) v = (k < Cin) ? wr[widx] : -wi[widx];
    else          v = (k < Cin) ? wi[widx] :  wr[widx];
    dst[idx] = __float2bfloat16(v);
  };
  if (bx < 1831) {                       // zero xp (7.5 MB)
    int i = bx * 256 + tid;
    if (i < 468512) xpz[i] = make_uint4(0, 0, 0, 0);
  } else if (bx < 1847) {                // wt1: [cg][t][u][ri], G=16
    int idx = (bx - 1831) * 256 + tid;
    if (idx < 2592) {
      int t = idx % 81;
      int co = idx / 81;
      int cg = co / 16, u = co % 16;
      int d = ((cg * 81 + t) * 16 + u) * 2;
      wt1[d] = w1r[idx];
      wt1[d + 1] = w1i[idx];
    }
  } else if (bx < 4439) {                // wt2b: B[t][n:128][k:64]
    int idx = (bx - 1847) * 256 + tid;
    int k = idx & 63, n = (idx >> 6) & 127, t = idx >> 13;
    int ci = k & 31, kin_i = k >> 5;
    int co = n & 63, out_i = n >> 6;
    int widx = (co * 32 + ci) * 81 + t;
    float v;
    if (out_i == 0) v = (kin_i == 0) ? w2r[widx] : -w2i[widx];
    else            v = (kin_i == 0) ? w2i[widx] :  w2r[widx];
    wt2b[idx] = __float2bfloat16(v);
  } else if (bx < 4567) {
    pack11(w3r, w3i, w3b, 128, 64, (bx - 4439) * 256 + tid);
  } else if (bx < 4823) {
    pack11(w4r, w4i, w4b, 128, 128, (bx - 4567) * 256 + tid);
  } else {
    pack11(w5r, w5i, w5b, 64, 128, (bx - 4823) * 256 + tid);
  }
}

__global__ __launch_bounds__(256) void cconv_l1(
    const float* __restrict__ xr, const float* __restrict__ xi,
    const float* __restrict__ wt, const float* __restrict__ br,
    const float* __restrict__ bi, __hip_bfloat16* __restrict__ xp) {
  __shared__ __align__(16) float lw[81 * 16 * 2];
  const int tid = threadIdx.x;
  const int cg = blockIdx.y;
  const int b = blockIdx.z;
  for (int i = tid; i < 2592; i += 256) lw[i] = wt[cg * 2592 + i];
  __syncthreads();

  int pos = blockIdx.x * 256 + tid;
  bool valid = pos < 6561;
  int p = valid ? pos : 6560;
  int d1 = p / 729, r = p % 729;
  int d2 = r / 81;
  r %= 81;
  int d3 = r / 9, d4 = r % 9;
  const int base = b * 160000 + d1 * 16000 + d2 * 800 + d3 * 40 + d4 * 2;
  const float* xrb = xr + base;
  const float* xib = xi + base;

  float2 acc[16];
#pragma unroll
  for (int u = 0; u < 16; ++u) acc[u] = make_float2(0.f, 0.f);

  for (int j1 = 0; j1 < 3; ++j1)
    for (int j2 = 0; j2 < 3; ++j2)
      for (int j3 = 0; j3 < 3; ++j3)
#pragma unroll
        for (int j4 = 0; j4 < 3; ++j4) {
          int t = ((j1 * 3 + j2) * 3 + j3) * 3 + j4;
          int xo = j1 * 8000 + j2 * 400 + j3 * 20 + j4;
          float xrv = xrb[xo], xiv = xib[xo];
          const float2* wv = (const float2*)&lw[t * 32];
#pragma unroll
          for (int u = 0; u < 16; ++u) {
            float2 w = wv[u];
            acc[u].x += xrv * w.x - xiv * w.y;
            acc[u].y += xrv * w.y + xiv * w.x;
          }
        }

  if (valid) {
    int q = (((d1 + 1) * 11 + (d2 + 1)) * 11 + (d3 + 1)) * 11 + (d4 + 1);
    __hip_bfloat16* xq = xp + ((size_t)(b * 14641 + q)) * 64 + cg * 16;
#pragma unroll
    for (int u = 0; u < 16; ++u) {
      int co = cg * 16 + u;
      xq[u] = __float2bfloat16(fmaxf(acc[u].x + br[co], 0.f));
      xq[32 + u] = __float2bfloat16(fmaxf(acc[u].y + bi[co], 0.f));
    }
  }
}

// ---- Layer 2: implicit-GEMM MFMA. 8 waves (2Mx4N), 128x128 tile, 3-buffer
//      stage-2-ahead with counted vmcnt. 2 waves/SIMD for latency hiding. ----
__global__ __launch_bounds__(512) void cconv2_mfma(
    const __hip_bfloat16* __restrict__ xp, const __hip_bfloat16* __restrict__ wb,
    const float* __restrict__ br, const float* __restrict__ bi,
    __hip_bfloat16* __restrict__ a2) {
  __shared__ __align__(128) char smem[98304];  // 3 x (A 16KB | B 16KB)
  const int tid = threadIdx.x;
  const int l = tid & 63, w = tid >> 6;        // 8 waves
  const int wm = w & 1, wn = w >> 1;           // 2M x 4N
  const int p0 = blockIdx.x * 128;

  const int swz = ((l & 7) ^ (l >> 3)) << 4;
  const char* xpB = (const char*)xp;
  const char* wB = (const char*)wb;
  int q00[2], rbB[2];
#pragma unroll
  for (int c = 0; c < 2; ++c) {
    int row = w * 16 + c * 8 + (l >> 3);
    int m = p0 + row;
    if (m > 26243) m = 26243;
    int b = m / 6561, p = m % 6561;
    int d1 = p / 729, r = p % 729;
    int d2 = r / 81;
    r %= 81;
    int d3 = r / 9, d4 = r % 9;
    q00[c] = b * 14641 + ((d1 * 11 + d2) * 11 + d3) * 11 + d4;
    rbB[c] = row * 128 + swz;
  }

  const int l15 = l & 15;
  const int klo = (l >> 4) << 4;
  const int sx = (l & 7) << 4;
  const int arow0 = (wm * 64 + l15) * 128;            // A rows: wm*64+mi*16
  const int brow0 = 16384 + (wn * 32 + l15) * 128;    // B rows: wn*32+ni*16

  f32x4 acc[4][2];
#pragma unroll
  for (int mi = 0; mi < 4; ++mi)
#pragma unroll
    for (int ni = 0; ni < 2; ++ni) acc[mi][ni] = (f32x4){0.f, 0.f, 0.f, 0.f};

  auto stage = [&](int t, int nb) {
    int j1 = t / 27, j2 = (t / 9) % 3, j3 = (t / 3) % 3, j4 = t % 3;
    int delta = ((j1 * 11 + j2) * 11 + j3) * 11 + j4;
#pragma unroll
    for (int c = 0; c < 2; ++c) {
      GLD16(xpB + (((size_t)(q00[c] + delta)) << 7) + swz,
            nb + w * 2048 + c * 1024);
      GLD16(wB + (((size_t)t) << 14) + rbB[c],
            nb + 16384 + w * 2048 + c * 1024);
    }
  };

  stage(0, 0);
  stage(1, 32768);

  int cur = 0;
  for (int t = 0; t < 81; ++t) {
    if (t < 80) {
      asm volatile("s_waitcnt vmcnt(4)" ::: "memory");
    } else {
      asm volatile("s_waitcnt vmcnt(0)" ::: "memory");
    }
    __builtin_amdgcn_s_barrier();
    if (t + 2 < 81) {
      int nb = cur + 2;
      if (nb >= 3) nb -= 3;
      stage(t + 2, nb * 32768);
    }
    const char* sb = smem + cur * 32768;
#pragma unroll
    for (int kh = 0; kh < 2; ++kh) {
      const int kx = ((kh << 6) + klo) ^ sx;
      bf16x8v af[4], bfr[2];
#pragma unroll
      for (int mi = 0; mi < 4; ++mi)
        af[mi] = *(const bf16x8v*)(sb + arow0 + mi * 2048 + kx);
#pragma unroll
      for (int ni = 0; ni < 2; ++ni)
        bfr[ni] = *(const bf16x8v*)(sb + brow0 + ni * 2048 + kx);
#pragma unroll
      for (int mi = 0; mi < 4; ++mi)
#pragma unroll
        for (int ni = 0; ni < 2; ++ni)
          acc[mi][ni] = __builtin_amdgcn_mfma_f32_16x16x32_bf16(
              af[mi], bfr[ni], acc[mi][ni], 0, 0, 0);
    }
    cur = (cur == 2) ? 0 : cur + 1;
  }

  const int prow = p0 + wm * 64 + ((l >> 4) << 2);
  const int col0 = wn * 32 + l15;
#pragma unroll
  for (int ni = 0; ni < 2; ++ni) {
    int cn = col0 + ni * 16;
    float bias = (cn < 64) ? br[cn] : bi[cn - 64];
#pragma unroll
    for (int mi = 0; mi < 4; ++mi)
#pragma unroll
      for (int j = 0; j < 4; ++j) {
        int m = prow + mi * 16 + j;
        if (m < 26244)
          a2[(size_t)m * 128 + cn] =
              __float2bfloat16(fmaxf(acc[mi][ni][j] + bias, 0.f));
      }
  }
}

// ---- Generic bf16 GEMM (2-buffer, 4 waves) ---------------------------------
__global__ __launch_bounds__(256) void gemm_bf16(
    const __hip_bfloat16* __restrict__ A, const __hip_bfloat16* __restrict__ Bm,
    const float* __restrict__ br, const float* __restrict__ bi,
    __hip_bfloat16* __restrict__ C, int M, int N, int K, int Cout,
    int stride2) {
  __shared__ __align__(128) char smem[65536];
  const int tid = threadIdx.x;
  const int l = tid & 63, w = tid >> 6;
  const int wm = w >> 1, wn = w & 1;
  const int p0 = blockIdx.x * 128;
  const int n0 = blockIdx.y * 128;
  const int nk = K >> 6;

  const int swz = ((l & 7) ^ (l >> 3)) << 4;
  const char* aB = (const char*)A;
  const char* bB = (const char*)Bm;
  size_t ofsA[4], ofsB[4];
#pragma unroll
  for (int c = 0; c < 4; ++c) {
    int row = w * 32 + c * 8 + (l >> 3);
    int m = p0 + row;
    if (m >= M) m = M - 1;
    int srcrow;
    if (stride2) {
      int bb = m / 625, r = m % 625;
      int d1 = r / 125;
      r %= 125;
      int d2 = r / 25;
      r %= 25;
      int d3 = r / 5, d4 = r % 5;
      srcrow = bb * 6561 + d1 * 1458 + d2 * 162 + d3 * 18 + d4 * 2;
    } else {
      srcrow = m;
    }
    ofsA[c] = (size_t)srcrow * (2 * K) + swz;
    ofsB[c] = (size_t)(n0 + row) * (2 * K) + swz;
  }

  const int l15 = l & 15;
  const int klo = (l >> 4) << 4;
  const int sx = (l & 7) << 4;
  const int arow0 = (wm * 64 + l15) * 128;
  const int brow0 = 16384 + (wn * 64 + l15) * 128;

  f32x4 acc[4][4];
#pragma unroll
  for (int mi = 0; mi < 4; ++mi)
#pragma unroll
    for (int ni = 0; ni < 4; ++ni) acc[mi][ni] = (f32x4){0.f, 0.f, 0.f, 0.f};

  auto stage = [&](int kt, int nb) {
#pragma unroll
    for (int c = 0; c < 4; ++c) {
      GLD16(aB + ofsA[c] + kt * 128, nb + w * 4096 + c * 1024);
      GLD16(bB + ofsB[c] + kt * 128, nb + 16384 + w * 4096 + c * 1024);
    }
  };

  stage(0, 0);
  __syncthreads();

  int cur = 0;
  for (int kt = 0; kt < nk; ++kt) {
    if (kt + 1 < nk) stage(kt + 1, (cur ^ 1) * 32768);
    const char* sb = smem + cur * 32768;
#pragma unroll
    for (int kh = 0; kh < 2; ++kh) {
      const int kx = ((kh << 6) + klo) ^ sx;
      bf16x8v af[4], bfr[4];
#pragma unroll
      for (int mi = 0; mi < 4; ++mi)
        af[mi] = *(const bf16x8v*)(sb + arow0 + mi * 2048 + kx);
#pragma unroll
      for (int ni = 0; ni < 4; ++ni)
        bfr[ni] = *(const bf16x8v*)(sb + brow0 + ni * 2048 + kx);
#pragma unroll
      for (int mi = 0; mi < 4; ++mi)
#pragma unroll
        for (int ni = 0; ni < 4; ++ni)
          acc[mi][ni] = __builtin_amdgcn_mfma_f32_16x16x32_bf16(
              af[mi], bfr[ni], acc[mi][ni], 0, 0, 0);
    }
    __syncthreads();
    cur ^= 1;
  }

  const int prow = p0 + wm * 64 + ((l >> 4) << 2);
  const int col0 = n0 + wn * 64 + l15;
#pragma unroll
  for (int ni = 0; ni < 4; ++ni) {
    int cn = col0 + ni * 16;
    float bias = (cn < Cout) ? br[cn] : bi[cn - Cout];
#pragma unroll
    for (int mi = 0; mi < 4; ++mi)
#pragma unroll
      for (int j = 0; j < 4; ++j) {
        int m = prow + mi * 16 + j;
        if (m < M)
          C[(size_t)m * N + cn] =
              __float2bfloat16(fmaxf(acc[mi][ni][j] + bias, 0.f));
      }
  }
}

__global__ __launch_bounds__(64) void fc_kernel(
    const __hip_bfloat16* __restrict__ a5, const float* __restrict__ fcw,
    const float* __restrict__ fcb, float* __restrict__ out) {
  int bc = blockIdx.x;
  int b = bc >> 6, c = bc & 63;
  int lane = threadIdx.x;
  const __hip_bfloat16* base = a5 + (size_t)b * 625 * 128;
  float sr = 0.f, si = 0.f;
  for (int p = lane; p < 625; p += 64) {
    float wv = fcw[p];
    sr += __bfloat162float(base[(size_t)p * 128 + c]) * wv;
    si += __bfloat162float(base[(size_t)p * 128 + 64 + c]) * wv;
  }
#pragma unroll
  for (int s = 32; s > 0; s >>= 1) {
    sr += __shfl_down(sr, s);
    si += __shfl_down(si, s);
  }
  if (lane == 0) {
    out[bc] = sr + fcb[0];
    out[256 + bc] = si;
  }
}

extern "C" void kernel_launch(void* const* d_in, const int* in_sizes, int n_in,
                              void* d_out, int out_size, void* d_ws,
                              size_t ws_size, hipStream_t stream) {
  const float* xr = (const float*)d_in[0];
  const float* xi = (const float*)d_in[1];
  const float* w1r = (const float*)d_in[2];
  const float* w1i = (const float*)d_in[3];
  const float* b1r = (const float*)d_in[4];
  const float* b1i = (const float*)d_in[5];
  const float* w2r = (const float*)d_in[6];
  const float* w2i = (const float*)d_in[7];
  const float* b2r = (const float*)d_in[8];
  const float* b2i = (const float*)d_in[9];
  const float* w3r = (const float*)d_in[10];
  const float* w3i = (const float*)d_in[11];
  const float* b3r = (const float*)d_in[12];
  const float* b3i = (const float*)d_in[13];
  const float* w4r = (const float*)d_in[14];
  const float* w4i = (const float*)d_in[15];
  const float* b4r = (const float*)d_in[16];
  const float* b4i = (const float*)d_in[17];
  const float* w5r = (const float*)d_in[18];
  const float* w5i = (const float*)d_in[19];
  const float* b5r = (const float*)d_in[20];
  const float* b5i = (const float*)d_in[21];
  const float* fcw = (const float*)d_in[22];
  const float* fcb = (const float*)d_in[23];
  float* out = (float*)d_out;

  float* ws = (float*)d_ws;
  float* wt1 = ws;                                        // 5184 f
  __hip_bfloat16* wt2b = (__hip_bfloat16*)(ws + 5184);    // 663552 bf16
  __hip_bfloat16* w3b = (__hip_bfloat16*)(ws + 336960);   // 32768 bf16
  __hip_bfloat16* w4b = (__hip_bfloat16*)(ws + 353344);   // 65536 bf16
  __hip_bfloat16* w5b = (__hip_bfloat16*)(ws + 386112);   // 32768 bf16
  __hip_bfloat16* xp = (__hip_bfloat16*)(ws + 402496);    // 3748096 bf16
  __hip_bfloat16* a2 = (__hip_bfloat16*)(ws + 2276544);   // 3359232 bf16
  __hip_bfloat16* a3 = (__hip_bfloat16*)(ws + 3956160);   // 6718464 bf16
  __hip_bfloat16* a4 = (__hip_bfloat16*)(ws + 7315392);   // 6718464 bf16
  __hip_bfloat16* a5 = (__hip_bfloat16*)(ws + 10674624);  // 320000 bf16

  prep_fused<<<dim3(4951), 256, 0, stream>>>(
      w1r, w1i, w2r, w2i, w3r, w3i, w4r, w4i, w5r, w5i, wt1, wt2b, w3b, w4b,
      w5b, (uint4*)xp);

  cconv_l1<<<dim3(26, 2, 4), 256, 0, stream>>>(xr, xi, wt1, b1r, b1i, xp);
  cconv2_mfma<<<dim3(206), 512, 0, stream>>>(xp, wt2b, b2r, b2i, a2);
  gemm_bf16<<<dim3(206, 2), 256, 0, stream>>>(a2, w3b, b3r, b3i, a3, 26244,
                                              256, 128, 128, 0);
  gemm_bf16<<<dim3(206, 2), 256, 0, stream>>>(a3, w4b, b4r, b4i, a4, 26244,
                                              256, 256, 128, 0);
  gemm_bf16<<<dim3(20, 1), 256, 0, stream>>>(a4, w5b, b5r, b5i, a5, 2500, 128,
                                             256, 64, 1);
  fc_kernel<<<dim3(256), 64, 0, stream>>>(a5, fcw, fcb, out);
}